// Round 9
// baseline (55.976 us; speedup 1.0000x reference)
//
#include <hip/hip_runtime.h>
#include <cstddef>

#define BATCH 512
#define UNITS 512
#define HID   64
#define CHUNKS 2                       // batch chunks of 256 rows
#define ROWS_PER_CHUNK (BATCH / CHUNKS)

typedef __bf16 bf16x8 __attribute__((ext_vector_type(8)));
typedef float  f32x4  __attribute__((ext_vector_type(4)));

// __builtin_amdgcn_rcpf = single v_rcp_f32 (vs ~10-inst IEEE div sequence);
// rel err ~1ulp -- negligible vs bf16-input absmax 0.0156.
__device__ __forceinline__ float fast_sigmoid(float v) {
    return __builtin_amdgcn_rcpf(1.0f + __expf(-v));
}
__device__ __forceinline__ float fast_tanh(float v) {
    return 2.0f * __builtin_amdgcn_rcpf(1.0f + __expf(-2.0f * v)) - 1.0f;
}

// R9 = R8 + CHUNKS=2 (grid 1024 -> 3 resident blocks/CU by LDS) + rcpf epilogue.
// R8 audit: 2 blocks/CU (grid-capped) -> 33% occupancy, 3.1 TB/s effective vs
// 174MB/27.6us pure-BW floor -> latency-bound. LDS 49KB allows 3 blocks/CU;
// grid was the cap. Cost of CHUNKS=2: W staged twice (~+25MB HBM, +4us) vs
// ~1.5x resident waves.
// Block: 512 thr = 8 waves x 16 rows, 128 rows/iter, 2 iters.
// LDS layout [g][ks][n][lg][lr] in 16B chunks (R7/R8-verified conflict-free):
//   compute read: g*8192 + ks*4096 + n*1024 + lane*16 (contig 1KB wave sweep)
//   staging write: g*8192 + tid*16 (linear)
__global__ __launch_bounds__(512, 3)
void gru_kernel(const float* __restrict__ x,    const float* __restrict__ h,
                const float* __restrict__ W_ir, const float* __restrict__ b_ir,
                const float* __restrict__ W_hr, const float* __restrict__ b_hr,
                const float* __restrict__ W_iz, const float* __restrict__ b_iz,
                const float* __restrict__ W_hz, const float* __restrict__ b_hz,
                const float* __restrict__ W_in, const float* __restrict__ b_in,
                const float* __restrict__ W_hn, const float* __restrict__ b_hn,
                float* __restrict__ out)
{
    __shared__ __align__(16) unsigned char wlds[6 * 512 * 16]; // 48 KB
    __shared__ float blds[4][64];                              // 1 KB

    const int u    = blockIdx.x >> 1;   // unit
    const int ck   = blockIdx.x & 1;    // batch chunk (256 rows)
    const int tid  = threadIdx.x;
    const int lane = tid & 63;
    const int w    = tid >> 6;   // 0..7 : 16-row group within 128-row tile
    const int lr   = lane & 15;  // row (A) / col (B,D) within fragment
    const int lg   = lane >> 4;  // k-group 0..3

    const float* Wg[6] = {
        W_ir + (size_t)u * 64 * 64, W_hr + (size_t)u * 64 * 64,
        W_iz + (size_t)u * 64 * 64, W_hz + (size_t)u * 64 * 64,
        W_in + (size_t)u * 64 * 64, W_hn + (size_t)u * 64 * 64 };

    // ---- stage weights: 6 passes (one per matrix), linear LDS writes ----
    // tid -> chunk: ks = tid>>8, n = (tid>>6)&3, lg_s = (tid>>4)&3, lr_s = tid&15
    // chunk holds W[ks*32+lg_s*8+e][n*16+lr_s], e = 0..7
    {
      const int ks_s = tid >> 8;
      const int n_s  = (tid >> 6) & 3;
      const int lg_s = (tid >> 4) & 3;
      const int lr_s = tid & 15;
      const int i0   = ks_s * 32 + lg_s * 8;
      const int o_s  = n_s * 16 + lr_s;
      #pragma unroll
      for (int g = 0; g < 6; ++g) {
        const float* q = Wg[g] + (size_t)i0 * 64 + o_s;
        bf16x8 f;
        #pragma unroll
        for (int e = 0; e < 8; ++e) f[e] = (__bf16)q[(size_t)e * 64];
        *(bf16x8*)(wlds + (size_t)(g * 512 + tid) * 16) = f;
      }
    }

    // ---- stage bias sums into LDS (1KB) ----
    if (tid < 256) {
      const int o_l = tid & 63;
      const int which = tid >> 6;
      const int o = u * 64 + o_l;
      float v;
      if      (which == 0) v = b_ir[o] + b_hr[o];
      else if (which == 1) v = b_iz[o] + b_hz[o];
      else if (which == 2) v = b_in[o];
      else                 v = b_hn[o];
      blds[which][o_l] = v;
    }

    __syncthreads();

    const f32x4 zero4 = { 0.0f, 0.0f, 0.0f, 0.0f };
    const int loff = lane * 16;

    #pragma unroll 1
    for (int it = 0; it < ROWS_PER_CHUNK / 128; ++it) {
      const int brow0 = ck * ROWS_PER_CHUNK + it * 128 + w * 16;

      // ---- A fragments: this wave's 16 rows of x,h (8 contiguous k/lane) ----
      bf16x8 ax[2], ah[2];
      {
        const int row = brow0 + lr;
        const float* px = x + ((size_t)row * UNITS + u) * HID;
        const float* ph = h + ((size_t)row * UNITS + u) * HID;
        #pragma unroll
        for (int ks = 0; ks < 2; ++ks) {
          const int i0 = ks * 32 + lg * 8;
          f32x4 xv0 = *(const f32x4*)(px + i0);
          f32x4 xv1 = *(const f32x4*)(px + i0 + 4);
          f32x4 hv0 = *(const f32x4*)(ph + i0);
          f32x4 hv1 = *(const f32x4*)(ph + i0 + 4);
          bf16x8 fx, fh;
          #pragma unroll
          for (int e = 0; e < 4; ++e) {
            fx[e]     = (__bf16)xv0[e];
            fx[4 + e] = (__bf16)xv1[e];
            fh[e]     = (__bf16)hv0[e];
            fh[4 + e] = (__bf16)hv1[e];
          }
          ax[ks] = fx;
          ah[ks] = fh;
        }
      }

      // ---- n-outer: one 16-col fragment at a time, 16 acc regs live ----
      #pragma unroll 1
      for (int n = 0; n < 4; ++n) {
        const int o = n * 16 + lr;

        // epilogue h reloads issued early (rows just touched -> L1 hits)
        float hv[4];
        #pragma unroll
        for (int j = 0; j < 4; ++j) {
          const int row = brow0 + lg * 4 + j;
          hv[j] = h[((size_t)row * UNITS + u) * HID + o];
        }
        const float br = blds[0][o];
        const float bz = blds[1][o];
        const float bi = blds[2][o];
        const float bh = blds[3][o];

        f32x4 accr = zero4, accz = zero4, acca = zero4, accb = zero4;
        #pragma unroll
        for (int ks = 0; ks < 2; ++ks) {
          const unsigned char* bp = wlds + ks * 4096 + n * 1024 + loff;
          bf16x8 b0 = *(const bf16x8*)(bp + 0 * 8192);
          bf16x8 b1 = *(const bf16x8*)(bp + 1 * 8192);
          bf16x8 b2 = *(const bf16x8*)(bp + 2 * 8192);
          bf16x8 b3 = *(const bf16x8*)(bp + 3 * 8192);
          bf16x8 b4 = *(const bf16x8*)(bp + 4 * 8192);
          bf16x8 b5 = *(const bf16x8*)(bp + 5 * 8192);
          accr = __builtin_amdgcn_mfma_f32_16x16x32_bf16(ax[ks], b0, accr, 0, 0, 0);
          accr = __builtin_amdgcn_mfma_f32_16x16x32_bf16(ah[ks], b1, accr, 0, 0, 0);
          accz = __builtin_amdgcn_mfma_f32_16x16x32_bf16(ax[ks], b2, accz, 0, 0, 0);
          accz = __builtin_amdgcn_mfma_f32_16x16x32_bf16(ah[ks], b3, accz, 0, 0, 0);
          acca = __builtin_amdgcn_mfma_f32_16x16x32_bf16(ax[ks], b4, acca, 0, 0, 0);
          accb = __builtin_amdgcn_mfma_f32_16x16x32_bf16(ah[ks], b5, accb, 0, 0, 0);
        }

        // ---- epilogue for this n ----
        // D layout (HW-verified m89): col = lane&15, row = (lane>>4)*4 + j
        #pragma unroll
        for (int j = 0; j < 4; ++j) {
          const int row = brow0 + lg * 4 + j;
          const size_t idx = ((size_t)row * UNITS + u) * HID + o;
          const float rv = fast_sigmoid(accr[j] + br);
          const float zv = fast_sigmoid(accz[j] + bz);
          const float nv = fast_tanh(acca[j] + bi + rv * (accb[j] + bh));
          out[idx] = (1.0f - zv) * nv + zv * hv[j];
        }
      }
    }
}

extern "C" void kernel_launch(void* const* d_in, const int* in_sizes, int n_in,
                              void* d_out, int out_size, void* d_ws, size_t ws_size,
                              hipStream_t stream) {
    const float* x    = (const float*)d_in[0];
    const float* h    = (const float*)d_in[1];
    const float* W_ir = (const float*)d_in[2];
    const float* b_ir = (const float*)d_in[3];
    const float* W_hr = (const float*)d_in[4];
    const float* b_hr = (const float*)d_in[5];
    const float* W_iz = (const float*)d_in[6];
    const float* b_iz = (const float*)d_in[7];
    const float* W_hz = (const float*)d_in[8];
    const float* b_hz = (const float*)d_in[9];
    const float* W_in = (const float*)d_in[10];
    const float* b_in = (const float*)d_in[11];
    const float* W_hn = (const float*)d_in[12];
    const float* b_hn = (const float*)d_in[13];
    float* out = (float*)d_out;

    gru_kernel<<<dim3(UNITS * CHUNKS), dim3(512), 0, stream>>>(
        x, h, W_ir, b_ir, W_hr, b_hr, W_iz, b_iz, W_hz, b_hz,
        W_in, b_in, W_hn, b_hn, out);
}

// Round 10
// 55.544 us; speedup vs baseline: 1.0078x; 1.0078x over previous
//
#include <hip/hip_runtime.h>
#include <cstddef>

#define BATCH 512
#define UNITS 512
#define HID   64

typedef __bf16 bf16x8 __attribute__((ext_vector_type(8)));
typedef float  f32x4  __attribute__((ext_vector_type(4)));

// single v_rcp_f32 (~1ulp) instead of IEEE div sequence; negligible vs bf16 error
__device__ __forceinline__ float fast_sigmoid(float v) {
    return __builtin_amdgcn_rcpf(1.0f + __expf(-v));
}
__device__ __forceinline__ float fast_tanh(float v) {
    return 2.0f * __builtin_amdgcn_rcpf(1.0f + __expf(-2.0f * v)) - 1.0f;
}

// R10 = R8 (CHUNKS=1, best traffic shape: W staged once, 174MB total) +
// cross-iteration software prefetch of x/h.
// R9 showed: VALUBusy halved with no dur change, occupancy pinned ~35%
// regardless of grid/LDS/regs -> ~90% stall, latency-bound, waves can't be
// added. So add ILP instead: issue iter i+1's global loads (raw f32x4, 32
// regs) under iter i's 48 MFMAs + epilogue; iter 0's loads issue BEFORE the
// weight-staging phase (hide under 48 staging loads).
// LDS layout [g][ks][n][lg][lr], 16B chunks (R7/R8-verified 0-conflict):
//   compute read: g*8192 + ks*4096 + n*1024 + lane*16 (contig 1KB wave sweep)
//   staging write: g*8192 + tid*16 (linear)
// launch_bounds (512,2): prefetch adds +32 regs over R8's 52; (512,3)'s ~85
// cap would spill (R2/R4 lesson: spill = scratch traffic disaster).
__global__ __launch_bounds__(512, 2)
void gru_kernel(const float* __restrict__ x,    const float* __restrict__ h,
                const float* __restrict__ W_ir, const float* __restrict__ b_ir,
                const float* __restrict__ W_hr, const float* __restrict__ b_hr,
                const float* __restrict__ W_iz, const float* __restrict__ b_iz,
                const float* __restrict__ W_hz, const float* __restrict__ b_hz,
                const float* __restrict__ W_in, const float* __restrict__ b_in,
                const float* __restrict__ W_hn, const float* __restrict__ b_hn,
                float* __restrict__ out)
{
    __shared__ __align__(16) unsigned char wlds[6 * 512 * 16]; // 48 KB
    __shared__ float blds[4][64];                              // 1 KB

    const int u    = blockIdx.x;
    const int tid  = threadIdx.x;
    const int lane = tid & 63;
    const int w    = tid >> 6;   // 0..7 : 16-row group within 128-row tile
    const int lr   = lane & 15;  // row (A) / col (B,D) within fragment
    const int lg   = lane >> 4;  // k-group 0..3

    // per-wave row base for iter 0; advance by 128 rows per iter
    const float* pxB = x + ((size_t)(w * 16 + lr) * UNITS + u) * HID;
    const float* phB = h + ((size_t)(w * 16 + lr) * UNITS + u) * HID;
    const size_t istep = (size_t)128 * UNITS * HID;

    // ---- iter-0 raw prefetch (issued before staging; hides under it) ----
    f32x4 rx0, rx1, rx2, rx3, rh0, rh1, rh2, rh3;
    {
      const int k0 = lg * 8;          // ks=0 base
      const int k1 = 32 + lg * 8;     // ks=1 base
      rx0 = *(const f32x4*)(pxB + k0);
      rx1 = *(const f32x4*)(pxB + k0 + 4);
      rx2 = *(const f32x4*)(pxB + k1);
      rx3 = *(const f32x4*)(pxB + k1 + 4);
      rh0 = *(const f32x4*)(phB + k0);
      rh1 = *(const f32x4*)(phB + k0 + 4);
      rh2 = *(const f32x4*)(phB + k1);
      rh3 = *(const f32x4*)(phB + k1 + 4);
    }

    const float* Wg[6] = {
        W_ir + (size_t)u * 64 * 64, W_hr + (size_t)u * 64 * 64,
        W_iz + (size_t)u * 64 * 64, W_hz + (size_t)u * 64 * 64,
        W_in + (size_t)u * 64 * 64, W_hn + (size_t)u * 64 * 64 };

    // ---- stage weights: 6 passes, linear LDS writes (R8-verified) ----
    {
      const int ks_s = tid >> 8;
      const int n_s  = (tid >> 6) & 3;
      const int lg_s = (tid >> 4) & 3;
      const int lr_s = tid & 15;
      const int i0   = ks_s * 32 + lg_s * 8;
      const int o_s  = n_s * 16 + lr_s;
      #pragma unroll
      for (int g = 0; g < 6; ++g) {
        const float* q = Wg[g] + (size_t)i0 * 64 + o_s;
        bf16x8 f;
        #pragma unroll
        for (int e = 0; e < 8; ++e) f[e] = (__bf16)q[(size_t)e * 64];
        *(bf16x8*)(wlds + (size_t)(g * 512 + tid) * 16) = f;
      }
    }

    // ---- stage bias sums into LDS (1KB) ----
    if (tid < 256) {
      const int o_l = tid & 63;
      const int which = tid >> 6;
      const int o = u * 64 + o_l;
      float v;
      if      (which == 0) v = b_ir[o] + b_hr[o];
      else if (which == 1) v = b_iz[o] + b_hz[o];
      else if (which == 2) v = b_in[o];
      else                 v = b_hn[o];
      blds[which][o_l] = v;
    }

    __syncthreads();

    const f32x4 zero4 = { 0.0f, 0.0f, 0.0f, 0.0f };
    const int loff = lane * 16;

    #pragma unroll 1
    for (int it = 0; it < 4; ++it) {
      const int brow0 = it * 128 + w * 16;

      // ---- pack A fragments from the prefetched raw values ----
      bf16x8 ax[2], ah[2];
      {
        bf16x8 f;
        #pragma unroll
        for (int e = 0; e < 4; ++e) { f[e] = (__bf16)rx0[e]; f[4+e] = (__bf16)rx1[e]; }
        ax[0] = f;
        #pragma unroll
        for (int e = 0; e < 4; ++e) { f[e] = (__bf16)rx2[e]; f[4+e] = (__bf16)rx3[e]; }
        ax[1] = f;
        #pragma unroll
        for (int e = 0; e < 4; ++e) { f[e] = (__bf16)rh0[e]; f[4+e] = (__bf16)rh1[e]; }
        ah[0] = f;
        #pragma unroll
        for (int e = 0; e < 4; ++e) { f[e] = (__bf16)rh2[e]; f[4+e] = (__bf16)rh3[e]; }
        ah[1] = f;
      }

      // ---- issue next iter's raw loads now; latency hides under 48 MFMAs ----
      if (it < 3) {
        const float* px = pxB + (size_t)(it + 1) * istep;
        const float* ph = phB + (size_t)(it + 1) * istep;
        const int k0 = lg * 8;
        const int k1 = 32 + lg * 8;
        rx0 = *(const f32x4*)(px + k0);
        rx1 = *(const f32x4*)(px + k0 + 4);
        rx2 = *(const f32x4*)(px + k1);
        rx3 = *(const f32x4*)(px + k1 + 4);
        rh0 = *(const f32x4*)(ph + k0);
        rh1 = *(const f32x4*)(ph + k0 + 4);
        rh2 = *(const f32x4*)(ph + k1);
        rh3 = *(const f32x4*)(ph + k1 + 4);
      }

      // ---- n-outer: one 16-col fragment at a time ----
      #pragma unroll 1
      for (int n = 0; n < 4; ++n) {
        const int o = n * 16 + lr;

        // epilogue h reloads (same rows as A-frags -> L1 hits), issued early
        float hv[4];
        #pragma unroll
        for (int j = 0; j < 4; ++j) {
          const int row = brow0 + lg * 4 + j;
          hv[j] = h[((size_t)row * UNITS + u) * HID + o];
        }
        const float br = blds[0][o];
        const float bz = blds[1][o];
        const float bi = blds[2][o];
        const float bh = blds[3][o];

        f32x4 accr = zero4, accz = zero4, acca = zero4, accb = zero4;
        #pragma unroll
        for (int ks = 0; ks < 2; ++ks) {
          const unsigned char* bp = wlds + ks * 4096 + n * 1024 + loff;
          bf16x8 b0 = *(const bf16x8*)(bp + 0 * 8192);
          bf16x8 b1 = *(const bf16x8*)(bp + 1 * 8192);
          bf16x8 b2 = *(const bf16x8*)(bp + 2 * 8192);
          bf16x8 b3 = *(const bf16x8*)(bp + 3 * 8192);
          bf16x8 b4 = *(const bf16x8*)(bp + 4 * 8192);
          bf16x8 b5 = *(const bf16x8*)(bp + 5 * 8192);
          accr = __builtin_amdgcn_mfma_f32_16x16x32_bf16(ax[ks], b0, accr, 0, 0, 0);
          accr = __builtin_amdgcn_mfma_f32_16x16x32_bf16(ah[ks], b1, accr, 0, 0, 0);
          accz = __builtin_amdgcn_mfma_f32_16x16x32_bf16(ax[ks], b2, accz, 0, 0, 0);
          accz = __builtin_amdgcn_mfma_f32_16x16x32_bf16(ah[ks], b3, accz, 0, 0, 0);
          acca = __builtin_amdgcn_mfma_f32_16x16x32_bf16(ax[ks], b4, acca, 0, 0, 0);
          accb = __builtin_amdgcn_mfma_f32_16x16x32_bf16(ah[ks], b5, accb, 0, 0, 0);
        }

        // ---- epilogue for this n ----
        // D layout (HW-verified m89): col = lane&15, row = (lane>>4)*4 + j
        #pragma unroll
        for (int j = 0; j < 4; ++j) {
          const int row = brow0 + lg * 4 + j;
          const size_t idx = ((size_t)row * UNITS + u) * HID + o;
          const float rv = fast_sigmoid(accr[j] + br);
          const float zv = fast_sigmoid(accz[j] + bz);
          const float nv = fast_tanh(acca[j] + bi + rv * (accb[j] + bh));
          out[idx] = (1.0f - zv) * nv + zv * hv[j];
        }
      }
    }
}

extern "C" void kernel_launch(void* const* d_in, const int* in_sizes, int n_in,
                              void* d_out, int out_size, void* d_ws, size_t ws_size,
                              hipStream_t stream) {
    const float* x    = (const float*)d_in[0];
    const float* h    = (const float*)d_in[1];
    const float* W_ir = (const float*)d_in[2];
    const float* b_ir = (const float*)d_in[3];
    const float* W_hr = (const float*)d_in[4];
    const float* b_hr = (const float*)d_in[5];
    const float* W_iz = (const float*)d_in[6];
    const float* b_iz = (const float*)d_in[7];
    const float* W_hz = (const float*)d_in[8];
    const float* b_hz = (const float*)d_in[9];
    const float* W_in = (const float*)d_in[10];
    const float* b_in = (const float*)d_in[11];
    const float* W_hn = (const float*)d_in[12];
    const float* b_hn = (const float*)d_in[13];
    float* out = (float*)d_out;

    gru_kernel<<<dim3(UNITS), dim3(512), 0, stream>>>(
        x, h, W_ir, b_ir, W_hr, b_hr, W_iz, b_iz, W_hz, b_hz,
        W_in, b_in, W_hn, b_hn, out);
}

// Round 11
// 50.971 us; speedup vs baseline: 1.0982x; 1.0897x over previous
//
#include <hip/hip_runtime.h>
#include <cstddef>

#define BATCH 512
#define UNITS 512
#define HID   64

typedef __bf16 bf16x8 __attribute__((ext_vector_type(8)));
typedef float  f32x4  __attribute__((ext_vector_type(4)));

// single v_rcp_f32 (~1ulp) instead of IEEE div sequence; negligible vs bf16 error
__device__ __forceinline__ float fast_sigmoid(float v) {
    return __builtin_amdgcn_rcpf(1.0f + __expf(-v));
}
__device__ __forceinline__ float fast_tanh(float v) {
    return 2.0f * __builtin_amdgcn_rcpf(1.0f + __expf(-2.0f * v)) - 1.0f;
}

// R11 = R8 (best: 55.6us) + XCD-aware block swizzle (T1). Single-variable test.
// Layout is [batch][unit][hid]: each block's x/h/out footprint is a 256B slice
// every 128KB, and W[u] is contiguous per unit. Default dispatch round-robins
// consecutive blocks over 8 XCDs -> each XCD L2 sees scattered 256B slices
// (poor DRAM row locality on x, h, out AND W). Swizzle gives each XCD a
// contiguous run of 64 units -> dense per-XCD footprint on all four streams.
// 512 blocks % 8 == 0 -> simple bijective form u=(bid&7)*64+(bid>>3) valid.
//
// R10 lesson (reverted): 1-iter-ahead prefetch of x/h evicted L2 before the
// epilogue h reload -> +23MB HBM, net zero. R9 lesson: occupancy knobs
// (grid/LDS/regs) are pinned ~35% and don't move dur; VALU/MFMA ~idle;
// effective BW 3.6 vs 6.3 TB/s is the gap -> attack memory locality.
// LDS layout [g][ks][n][lg][lr], 16B chunks (R7/R8-verified 0-conflict):
//   compute read: g*8192 + ks*4096 + n*1024 + lane*16 (contig 1KB wave sweep)
//   staging write: g*8192 + tid*16 (linear)
__global__ __launch_bounds__(512, 3)
void gru_kernel(const float* __restrict__ x,    const float* __restrict__ h,
                const float* __restrict__ W_ir, const float* __restrict__ b_ir,
                const float* __restrict__ W_hr, const float* __restrict__ b_hr,
                const float* __restrict__ W_iz, const float* __restrict__ b_iz,
                const float* __restrict__ W_hz, const float* __restrict__ b_hz,
                const float* __restrict__ W_in, const float* __restrict__ b_in,
                const float* __restrict__ W_hn, const float* __restrict__ b_hn,
                float* __restrict__ out)
{
    __shared__ __align__(16) unsigned char wlds[6 * 512 * 16]; // 48 KB
    __shared__ float blds[4][64];                              // 1 KB

    // XCD swizzle: dispatch sends bid%8 to XCD (bid&7); give each XCD a
    // contiguous 64-unit range.
    const int u    = (blockIdx.x & 7) * 64 + (blockIdx.x >> 3);
    const int tid  = threadIdx.x;
    const int lane = tid & 63;
    const int w    = tid >> 6;   // 0..7 : 16-row group within 128-row tile
    const int lr   = lane & 15;  // row (A) / col (B,D) within fragment
    const int lg   = lane >> 4;  // k-group 0..3

    const float* Wg[6] = {
        W_ir + (size_t)u * 64 * 64, W_hr + (size_t)u * 64 * 64,
        W_iz + (size_t)u * 64 * 64, W_hz + (size_t)u * 64 * 64,
        W_in + (size_t)u * 64 * 64, W_hn + (size_t)u * 64 * 64 };

    // ---- stage weights: 6 passes (one per matrix), linear LDS writes ----
    // tid -> chunk: ks = tid>>8, n = (tid>>6)&3, lg_s = (tid>>4)&3, lr_s = tid&15
    // chunk holds W[ks*32+lg_s*8+e][n*16+lr_s], e = 0..7
    {
      const int ks_s = tid >> 8;
      const int n_s  = (tid >> 6) & 3;
      const int lg_s = (tid >> 4) & 3;
      const int lr_s = tid & 15;
      const int i0   = ks_s * 32 + lg_s * 8;
      const int o_s  = n_s * 16 + lr_s;
      #pragma unroll
      for (int g = 0; g < 6; ++g) {
        const float* q = Wg[g] + (size_t)i0 * 64 + o_s;
        bf16x8 f;
        #pragma unroll
        for (int e = 0; e < 8; ++e) f[e] = (__bf16)q[(size_t)e * 64];
        *(bf16x8*)(wlds + (size_t)(g * 512 + tid) * 16) = f;
      }
    }

    // ---- stage bias sums into LDS (1KB) ----
    if (tid < 256) {
      const int o_l = tid & 63;
      const int which = tid >> 6;
      const int o = u * 64 + o_l;
      float v;
      if      (which == 0) v = b_ir[o] + b_hr[o];
      else if (which == 1) v = b_iz[o] + b_hz[o];
      else if (which == 2) v = b_in[o];
      else                 v = b_hn[o];
      blds[which][o_l] = v;
    }

    __syncthreads();

    const f32x4 zero4 = { 0.0f, 0.0f, 0.0f, 0.0f };
    const int loff = lane * 16;

    #pragma unroll 1
    for (int it = 0; it < 4; ++it) {
      const int brow0 = it * 128 + w * 16;

      // ---- A fragments: this wave's 16 rows of x,h (8 contiguous k/lane) ----
      bf16x8 ax[2], ah[2];
      {
        const int row = brow0 + lr;
        const float* px = x + ((size_t)row * UNITS + u) * HID;
        const float* ph = h + ((size_t)row * UNITS + u) * HID;
        #pragma unroll
        for (int ks = 0; ks < 2; ++ks) {
          const int i0 = ks * 32 + lg * 8;
          f32x4 xv0 = *(const f32x4*)(px + i0);
          f32x4 xv1 = *(const f32x4*)(px + i0 + 4);
          f32x4 hv0 = *(const f32x4*)(ph + i0);
          f32x4 hv1 = *(const f32x4*)(ph + i0 + 4);
          bf16x8 fx, fh;
          #pragma unroll
          for (int e = 0; e < 4; ++e) {
            fx[e]     = (__bf16)xv0[e];
            fx[4 + e] = (__bf16)xv1[e];
            fh[e]     = (__bf16)hv0[e];
            fh[4 + e] = (__bf16)hv1[e];
          }
          ax[ks] = fx;
          ah[ks] = fh;
        }
      }

      // ---- n-outer: one 16-col fragment at a time, 16 acc regs live ----
      #pragma unroll 1
      for (int n = 0; n < 4; ++n) {
        const int o = n * 16 + lr;

        // epilogue h reloads issued early (rows just touched -> L1 hits)
        float hv[4];
        #pragma unroll
        for (int j = 0; j < 4; ++j) {
          const int row = brow0 + lg * 4 + j;
          hv[j] = h[((size_t)row * UNITS + u) * HID + o];
        }
        const float br = blds[0][o];
        const float bz = blds[1][o];
        const float bi = blds[2][o];
        const float bh = blds[3][o];

        f32x4 accr = zero4, accz = zero4, acca = zero4, accb = zero4;
        #pragma unroll
        for (int ks = 0; ks < 2; ++ks) {
          const unsigned char* bp = wlds + ks * 4096 + n * 1024 + loff;
          bf16x8 b0 = *(const bf16x8*)(bp + 0 * 8192);
          bf16x8 b1 = *(const bf16x8*)(bp + 1 * 8192);
          bf16x8 b2 = *(const bf16x8*)(bp + 2 * 8192);
          bf16x8 b3 = *(const bf16x8*)(bp + 3 * 8192);
          bf16x8 b4 = *(const bf16x8*)(bp + 4 * 8192);
          bf16x8 b5 = *(const bf16x8*)(bp + 5 * 8192);
          accr = __builtin_amdgcn_mfma_f32_16x16x32_bf16(ax[ks], b0, accr, 0, 0, 0);
          accr = __builtin_amdgcn_mfma_f32_16x16x32_bf16(ah[ks], b1, accr, 0, 0, 0);
          accz = __builtin_amdgcn_mfma_f32_16x16x32_bf16(ax[ks], b2, accz, 0, 0, 0);
          accz = __builtin_amdgcn_mfma_f32_16x16x32_bf16(ah[ks], b3, accz, 0, 0, 0);
          acca = __builtin_amdgcn_mfma_f32_16x16x32_bf16(ax[ks], b4, acca, 0, 0, 0);
          accb = __builtin_amdgcn_mfma_f32_16x16x32_bf16(ah[ks], b5, accb, 0, 0, 0);
        }

        // ---- epilogue for this n ----
        // D layout (HW-verified m89): col = lane&15, row = (lane>>4)*4 + j
        #pragma unroll
        for (int j = 0; j < 4; ++j) {
          const int row = brow0 + lg * 4 + j;
          const size_t idx = ((size_t)row * UNITS + u) * HID + o;
          const float rv = fast_sigmoid(accr[j] + br);
          const float zv = fast_sigmoid(accz[j] + bz);
          const float nv = fast_tanh(acca[j] + bi + rv * (accb[j] + bh));
          out[idx] = (1.0f - zv) * nv + zv * hv[j];
        }
      }
    }
}

extern "C" void kernel_launch(void* const* d_in, const int* in_sizes, int n_in,
                              void* d_out, int out_size, void* d_ws, size_t ws_size,
                              hipStream_t stream) {
    const float* x    = (const float*)d_in[0];
    const float* h    = (const float*)d_in[1];
    const float* W_ir = (const float*)d_in[2];
    const float* b_ir = (const float*)d_in[3];
    const float* W_hr = (const float*)d_in[4];
    const float* b_hr = (const float*)d_in[5];
    const float* W_iz = (const float*)d_in[6];
    const float* b_iz = (const float*)d_in[7];
    const float* W_hz = (const float*)d_in[8];
    const float* b_hz = (const float*)d_in[9];
    const float* W_in = (const float*)d_in[10];
    const float* b_in = (const float*)d_in[11];
    const float* W_hn = (const float*)d_in[12];
    const float* b_hn = (const float*)d_in[13];
    float* out = (float*)d_out;

    gru_kernel<<<dim3(UNITS), dim3(512), 0, stream>>>(
        x, h, W_ir, b_ir, W_hr, b_hr, W_iz, b_iz, W_hz, b_hz,
        W_in, b_in, W_hn, b_hn, out);
}